// Round 5
// baseline (524.246 us; speedup 1.0000x reference)
//
#include <hip/hip_runtime.h>
#include <hip/hip_bf16.h>
#include <stdint.h>

typedef unsigned short u16;
typedef __bf16 bf16_t;
typedef bf16_t bf16x8 __attribute__((ext_vector_type(8)));
typedef float f32x4 __attribute__((ext_vector_type(4)));

// f32 -> bf16 RNE (scalar)
__device__ __forceinline__ u16 f2b(float f) {
    union { float f; uint32_t i; } v; v.f = f;
    uint32_t r = v.i + 0x7FFFu + ((v.i >> 16) & 1u);
    return (u16)(r >> 16);
}
// packed f32x2 -> bf16x2 (v_cvt_pk_bf16_f32)
__device__ __forceinline__ uint32_t pk2(float a, float b) {
    __hip_bfloat162 h = __float22bfloat162_rn(float2{a, b});
    return *(const uint32_t*)&h;
}
__device__ __forceinline__ uint4 pack8(float4 lo, float4 hi) {
    uint4 r;
    r.x = pk2(lo.x, lo.y); r.y = pk2(lo.z, lo.w);
    r.z = pk2(hi.x, hi.y); r.w = pk2(hi.z, hi.w);
    return r;
}

// ---------------- GEMM core: C[M,N] = X[M,1024] @ W[1024,N] + bias ----------------
// WT = W^T bf16 [N][K]. 128x128 tile, BK=32, 2x2 wave quadrants, 4x4 16x16x32 frags.
// Prefetch: tile kt+1's global loads issued after barrier (b) of tile kt, drained at
// the compiler's vmcnt(0) before barrier (a) of kt+1 -> latency overlaps compute.
// mode 0: bf16 scatter-store to [B,H,S,D]; mode 1: float32 row-major [M,1024]
template<bool XF32>
__device__ __forceinline__ void gemm128(const void* __restrict__ Xv,
                                        const u16* __restrict__ WT,
                                        const float* __restrict__ bias,
                                        u16* __restrict__ dstb,
                                        float* __restrict__ dstf, int mode)
{
    __shared__ __align__(16) u16 As[128 * 32];
    __shared__ __align__(16) u16 Bs[128 * 32];
    const int t    = threadIdx.x;
    const int lane = t & 63;
    const int quad = lane >> 4;
    const int l15  = lane & 15;
    const int kc   = quad * 8;
    const int m0 = blockIdx.y * 128;
    const int n0 = blockIdx.x * 128;
    const int wave = t >> 6;
    const int wm = (wave >> 1) * 64;
    const int wn = (wave & 1) * 64;

    f32x4 acc[4][4];
#pragma unroll
    for (int i = 0; i < 4; i++)
#pragma unroll
        for (int j = 0; j < 4; j++)
#pragma unroll
            for (int r = 0; r < 4; r++) acc[i][j][r] = 0.0f;

    const int ar = t >> 2;
    const int ac = (t & 3) * 8;
    const float* xg32 = (const float*)Xv + (m0 + ar) * 1024 + ac;
    const u16*   xg16 = (const u16*)Xv   + (m0 + ar) * 1024 + ac;
    const u16*   wg   = WT + (n0 + ar) * 1024 + ac;

    // preload tile 0
    float4 fa0l, fa0h, fa1l, fa1h;
    uint4 a0, a1, b0, b1;
    if (XF32) {
        fa0l = *(const float4*)(xg32);
        fa0h = *(const float4*)(xg32 + 4);
        fa1l = *(const float4*)(xg32 + 64 * 1024);
        fa1h = *(const float4*)(xg32 + 64 * 1024 + 4);
    } else {
        a0 = *(const uint4*)(xg16);
        a1 = *(const uint4*)(xg16 + 64 * 1024);
    }
    b0 = *(const uint4*)(wg);
    b1 = *(const uint4*)(wg + 64 * 1024);

    for (int kt = 0; kt < 1024; kt += 32) {
        __syncthreads();                    // (a) prev frag reads done; vmcnt drained
        if (XF32) {
            *(uint4*)&As[t * 8]         = pack8(fa0l, fa0h);
            *(uint4*)&As[(t + 256) * 8] = pack8(fa1l, fa1h);
        } else {
            *(uint4*)&As[t * 8]         = a0;
            *(uint4*)&As[(t + 256) * 8] = a1;
        }
        *(uint4*)&Bs[t * 8]         = b0;
        *(uint4*)&Bs[(t + 256) * 8] = b1;
        __syncthreads();                    // (b) staging visible
        if (kt + 32 < 1024) {               // prefetch next tile (overlaps MFMA below)
            const int kn = kt + 32;
            if (XF32) {
                fa0l = *(const float4*)(xg32 + kn);
                fa0h = *(const float4*)(xg32 + kn + 4);
                fa1l = *(const float4*)(xg32 + 64 * 1024 + kn);
                fa1h = *(const float4*)(xg32 + 64 * 1024 + kn + 4);
            } else {
                a0 = *(const uint4*)(xg16 + kn);
                a1 = *(const uint4*)(xg16 + 64 * 1024 + kn);
            }
            b0 = *(const uint4*)(wg + kn);
            b1 = *(const uint4*)(wg + 64 * 1024 + kn);
        }
        bf16x8 af[4], bfv[4];
#pragma unroll
        for (int i = 0; i < 4; i++) {
            af[i]  = *(const bf16x8*)&As[(wm + i * 16 + l15) * 32 + kc];
            bfv[i] = *(const bf16x8*)&Bs[(wn + i * 16 + l15) * 32 + kc];
        }
#pragma unroll
        for (int i = 0; i < 4; i++)
#pragma unroll
            for (int j = 0; j < 4; j++)
                acc[i][j] = __builtin_amdgcn_mfma_f32_16x16x32_bf16(af[i], bfv[j], acc[i][j], 0, 0, 0);
    }

    // epilogue: C row = quad*4 + r, col = lane&15 (HW-verified R4)
#pragma unroll
    for (int i = 0; i < 4; i++) {
        const int rb = m0 + wm + i * 16 + quad * 4;
#pragma unroll
        for (int j = 0; j < 4; j++) {
            const int col = n0 + wn + j * 16 + l15;
            const float bias_v = bias[col];
#pragma unroll
            for (int r = 0; r < 4; r++) {
                const float v = acc[i][j][r] + bias_v;
                const int gm = rb + r;
                if (mode == 0) {
                    const int b = gm >> 11, s = gm & 2047;
                    const int h = col >> 6, d = col & 63;
                    dstb[((b * 16 + h) * 2048 + s) * 64 + d] = f2b(v);
                } else {
                    dstf[gm * 1024 + col] = v;
                }
            }
        }
    }
}

__global__ __launch_bounds__(256)
void qkv_kernel(const float* __restrict__ q_in, const float* __restrict__ k_in,
                const float* __restrict__ v_in, const u16* __restrict__ WT,
                const float* __restrict__ bq, const float* __restrict__ bk,
                const float* __restrict__ bv,
                u16* __restrict__ Qo, u16* __restrict__ Ko, u16* __restrict__ Vo)
{
    const int z = blockIdx.z;
    const float* X   = (z == 0) ? q_in : (z == 1) ? k_in : v_in;
    const u16* wt    = WT + ((z == 0) ? 2 : (z == 1) ? 1 : 0) * (1024 * 1024);
    const float* bias= (z == 0) ? bq : (z == 1) ? bk : bv;
    u16* dst         = (z == 0) ? Qo : (z == 1) ? Ko : Vo;
    gemm128<true>(X, wt, bias, dst, nullptr, 0);
}

__global__ __launch_bounds__(256)
void oproj_kernel(const u16* __restrict__ AO, const u16* __restrict__ WT,
                  const float* __restrict__ bo, float* __restrict__ out)
{
    gemm128<false>(AO, WT + 3 * 1024 * 1024, bo, nullptr, out, 1);
}

// ---------------- weight transpose+cvt: W[1024 k][1024 n] f32 -> WT[n][k] bf16 ----
__global__ void transpose_w(const float* __restrict__ Wv, const float* __restrict__ Wk,
                            const float* __restrict__ Wq, const float* __restrict__ Wo,
                            u16* __restrict__ WT)
{
    __shared__ u16 tile[64][65];
    const int z = blockIdx.z;
    const float* W = (z == 0) ? Wv : (z == 1) ? Wk : (z == 2) ? Wq : Wo;
    u16* dst = WT + z * 1024 * 1024;
    const int r0 = blockIdx.y * 64, c0 = blockIdx.x * 64;
    const int col = threadIdx.x & 63, rb = threadIdx.x >> 6;
#pragma unroll
    for (int r = rb; r < 64; r += 4) tile[r][col] = f2b(W[(r0 + r) * 1024 + c0 + col]);
    __syncthreads();
#pragma unroll
    for (int r = rb; r < 64; r += 4) dst[(c0 + r) * 1024 + r0 + col] = tile[col][r];
}

// ---------------- V transpose: V[bh][2048 s][64 d] -> VT[bh][64 d][2048 s] --------
__global__ void transpose_v(const u16* __restrict__ V, u16* __restrict__ VT)
{
    __shared__ u16 tile[64][65];
    const int bh = blockIdx.y, s0 = blockIdx.x * 64;
    const int col = threadIdx.x & 63, rb = threadIdx.x >> 6;
    const u16* src = V + bh * 2048 * 64;
    u16* dst = VT + bh * 64 * 2048;
#pragma unroll
    for (int r = rb; r < 64; r += 4) tile[r][col] = src[(s0 + r) * 64 + col];
    __syncthreads();
#pragma unroll
    for (int r = rb; r < 64; r += 4) dst[r * 2048 + s0 + col] = tile[col][r];
}

// ---------------- flash attention (transposed): Tq=64/block, Tk=128 KV tiles -------
// S^T = K·Q^T so C-layout col = q-row = l15: each lane owns ONE q-row's scores ->
// per-lane online softmax, 2 cross-quad shuffles, scalar m/l/alpha. PV computed as
// O^T = V^T·P^T; P stored [qrow][kv] (wave-private rows) and read back as B-operand
// with contiguous b128 reads. 2 barriers/iter; P round-trip fenced per-wave via
// s_waitcnt lgkmcnt(0). K/V tiles prefetched into VGPRs one iter ahead.
__global__ __launch_bounds__(256, 2)
void attn_kernel(const u16* __restrict__ Q, const u16* __restrict__ K,
                 const u16* __restrict__ VT, u16* __restrict__ AO)
{
    __shared__ __align__(16) u16 Qs[64 * 72];
    __shared__ __align__(16) u16 Ks[128 * 72];
    __shared__ __align__(16) u16 Ps[64 * 136];
    __shared__ __align__(16) u16 Vts[64 * 136];

    const int t    = threadIdx.x;
    const int lane = t & 63;
    const int wave = t >> 6;
    const int quad = lane >> 4;
    const int l15  = lane & 15;
    const int kc   = quad * 8;
    const int bh = blockIdx.y;
    const int qt = blockIdx.x;

    const u16* Qg = Q + (bh * 2048 + qt * 64) * 64;
    const u16* Kg = K + bh * 2048 * 64;
    const u16* Vg = VT + bh * 64 * 2048;

    // stage Q once; fold 0.125 * log2(e) so softmax runs in exp2 domain
#pragma unroll
    for (int c = 0; c < 2; c++) {
        const int chunk = t + c * 256;
        const int row = chunk >> 3;
        const int col = (chunk & 7) * 8;
        uint4 dv = *(const uint4*)&Qg[row * 64 + col];
        u16 tmp[8];
        *(uint4*)tmp = dv;
        float f[8];
#pragma unroll
        for (int i = 0; i < 8; i++) {
            union { float f; uint32_t u; } x; x.u = ((uint32_t)tmp[i]) << 16;
            f[i] = x.f * 0.18033688f;   // 0.125 * log2e
        }
        uint4 pk;
        pk.x = pk2(f[0], f[1]); pk.y = pk2(f[2], f[3]);
        pk.z = pk2(f[4], f[5]); pk.w = pk2(f[6], f[7]);
        *(uint4*)&Qs[row * 72 + col] = pk;
    }

    f32x4 o[4];
#pragma unroll
    for (int dj = 0; dj < 4; dj++)
#pragma unroll
        for (int r = 0; r < 4; r++) o[dj][r] = 0.0f;
    float m_st = -1.0e30f, l_st = 0.0f;

    // preload KV tile 0
    uint4 kreg[4], vreg[4];
#pragma unroll
    for (int c = 0; c < 4; c++) {
        const int chunk = t + c * 256;
        kreg[c] = *(const uint4*)&Kg[(chunk >> 3) * 64 + (chunk & 7) * 8];
        vreg[c] = *(const uint4*)&Vg[(chunk >> 4) * 2048 + (chunk & 15) * 8];
    }

    for (int kv = 0; kv < 16; kv++) {
        __syncthreads();   // (a) prev tile's LDS reads done; vmcnt drained (prefetch)
#pragma unroll
        for (int c = 0; c < 4; c++) {
            const int chunk = t + c * 256;
            *(uint4*)&Ks[(chunk >> 3) * 72 + (chunk & 7) * 8]   = kreg[c];
            *(uint4*)&Vts[(chunk >> 4) * 136 + (chunk & 15) * 8] = vreg[c];
        }
        __syncthreads();   // (b) staging visible
        if (kv < 15) {     // prefetch next tile — overlaps the whole compute phase
            const int j0n = (kv + 1) * 128;
#pragma unroll
            for (int c = 0; c < 4; c++) {
                const int chunk = t + c * 256;
                kreg[c] = *(const uint4*)&Kg[(j0n + (chunk >> 3)) * 64 + (chunk & 7) * 8];
                vreg[c] = *(const uint4*)&Vg[(chunk >> 4) * 2048 + j0n + (chunk & 15) * 8];
            }
        }

        // S^T = K·Q^T : frag n covers kv rows n*16..+15, cols = 16 q-rows of this wave
        f32x4 s[8];
#pragma unroll
        for (int n = 0; n < 8; n++)
#pragma unroll
            for (int r = 0; r < 4; r++) s[n][r] = 0.0f;
#pragma unroll
        for (int kk = 0; kk < 64; kk += 32) {
            const bf16x8 bq = *(const bf16x8*)&Qs[(wave * 16 + l15) * 72 + kk + kc];
#pragma unroll
            for (int n = 0; n < 8; n++) {
                const bf16x8 ak = *(const bf16x8*)&Ks[(n * 16 + l15) * 72 + kk + kc];
                s[n] = __builtin_amdgcn_mfma_f32_16x16x32_bf16(ak, bq, s[n], 0, 0, 0);
            }
        }

        // per-lane online softmax (q-row = l15; lane holds kv = n*16+quad*4+r)
        float mx = s[0][0];
#pragma unroll
        for (int n = 0; n < 8; n++)
#pragma unroll
            for (int r = 0; r < 4; r++) mx = fmaxf(mx, s[n][r]);
        mx = fmaxf(mx, __shfl_xor(mx, 16));
        mx = fmaxf(mx, __shfl_xor(mx, 32));
        const float mnew = fmaxf(m_st, mx);
        const float alpha = exp2f(m_st - mnew);
        m_st = mnew;
        float sum = 0.0f;
#pragma unroll
        for (int n = 0; n < 8; n++)
#pragma unroll
            for (int r = 0; r < 4; r++) {
                const float p = exp2f(s[n][r] - m_st);
                s[n][r] = p;
                sum += p;
            }
        sum += __shfl_xor(sum, 16);
        sum += __shfl_xor(sum, 32);
        l_st = l_st * alpha + sum;
#pragma unroll
        for (int dj = 0; dj < 4; dj++)
#pragma unroll
            for (int r = 0; r < 4; r++) o[dj][r] *= alpha;

        // P[qrow][kv] -> LDS: r=0..3 are consecutive kv cols -> packed b64 stores
#pragma unroll
        for (int n = 0; n < 8; n++) {
            uint2 pk;
            pk.x = pk2(s[n][0], s[n][1]);
            pk.y = pk2(s[n][2], s[n][3]);
            *(uint2*)&Ps[(wave * 16 + l15) * 136 + n * 16 + quad * 4] = pk;
        }
        // wave-private round-trip: order the b64 writes before the b128 reads
        asm volatile("s_waitcnt lgkmcnt(0)" ::: "memory");

        // O^T += V^T · P^T : A = V^T[d][kv] frags, B-operand = contiguous P rows
#pragma unroll
        for (int ks = 0; ks < 4; ks++) {
            const bf16x8 bp = *(const bf16x8*)&Ps[(wave * 16 + l15) * 136 + ks * 32 + kc];
#pragma unroll
            for (int dj = 0; dj < 4; dj++) {
                const bf16x8 av = *(const bf16x8*)&Vts[(dj * 16 + l15) * 136 + ks * 32 + kc];
                o[dj] = __builtin_amdgcn_mfma_f32_16x16x32_bf16(av, bp, o[dj], 0, 0, 0);
            }
        }
    }

    // epilogue: O^T[d = dj*16+quad*4+r][qrow = l15]; write bf16 [B,S,E] packed b64
    const int b = bh >> 4, h = bh & 15;
    const int sq = qt * 64 + wave * 16 + l15;
    const float inv = 1.0f / l_st;
#pragma unroll
    for (int dj = 0; dj < 4; dj++) {
        uint2 pk;
        pk.x = pk2(o[dj][0] * inv, o[dj][1] * inv);
        pk.y = pk2(o[dj][2] * inv, o[dj][3] * inv);
        *(uint2*)&AO[(b * 2048 + sq) * 1024 + h * 64 + dj * 16 + quad * 4] = pk;
    }
}

extern "C" void kernel_launch(void* const* d_in, const int* in_sizes, int n_in,
                              void* d_out, int out_size, void* d_ws, size_t ws_size,
                              hipStream_t stream)
{
    (void)in_sizes; (void)n_in; (void)out_size; (void)ws_size;
    const float* value = (const float*)d_in[0];
    const float* key_  = (const float*)d_in[1];
    const float* query = (const float*)d_in[2];
    const float* Wv = (const float*)d_in[3];
    const float* bv = (const float*)d_in[4];
    const float* Wk = (const float*)d_in[5];
    const float* bk = (const float*)d_in[6];
    const float* Wq = (const float*)d_in[7];
    const float* bq = (const float*)d_in[8];
    const float* Wo = (const float*)d_in[9];
    const float* bo = (const float*)d_in[10];

    u16* ws = (u16*)d_ws;
    u16* WT = ws;                          // 4 x 1M bf16 (order: v,k,q,o)
    u16* Q  = ws + 4 * 1024 * 1024;        // 8M bf16 [B,H,S,D]
    u16* K  = Q + 8 * 1024 * 1024;         // 8M
    u16* V  = K + 8 * 1024 * 1024;         // 8M; dead after transpose_v -> reused as AO
    u16* VTr= V + 8 * 1024 * 1024;         // 8M [B,H,D,S]
    u16* AO = V;                           // alias: V consumed before attn writes AO

    transpose_w<<<dim3(16, 16, 4), dim3(256), 0, stream>>>(Wv, Wk, Wq, Wo, WT);
    qkv_kernel<<<dim3(8, 64, 3), dim3(256), 0, stream>>>(query, key_, value, WT,
                                                         bq, bk, bv, Q, K, V);
    transpose_v<<<dim3(32, 64), dim3(256), 0, stream>>>(V, VTr);
    attn_kernel<<<dim3(32, 64), dim3(256), 0, stream>>>(Q, K, VTr, AO);
    oproj_kernel<<<dim3(8, 64, 1), dim3(256), 0, stream>>>(AO, WT, bo, (float*)d_out);
}

// Round 6
// 453.944 us; speedup vs baseline: 1.1549x; 1.1549x over previous
//
#include <hip/hip_runtime.h>
#include <hip/hip_bf16.h>
#include <stdint.h>

typedef unsigned short u16;
typedef __bf16 bf16_t;
typedef bf16_t bf16x8 __attribute__((ext_vector_type(8)));
typedef float f32x4 __attribute__((ext_vector_type(4)));

__device__ __forceinline__ u16 f2b(float f) {
    union { float f; uint32_t i; } v; v.f = f;
    uint32_t r = v.i + 0x7FFFu + ((v.i >> 16) & 1u);
    return (u16)(r >> 16);
}
__device__ __forceinline__ uint32_t pk2(float a, float b) {
    __hip_bfloat162 h = __float22bfloat162_rn(float2{a, b});
    return *(const uint32_t*)&h;
}
__device__ __forceinline__ uint4 pack8(float4 lo, float4 hi) {
    uint4 r;
    r.x = pk2(lo.x, lo.y); r.y = pk2(lo.z, lo.w);
    r.z = pk2(hi.x, hi.y); r.w = pk2(hi.z, hi.w);
    return r;
}
// async global->LDS DMA, 16B per lane (m97 idiom: LDS dst linear in lane)
__device__ __forceinline__ void async16(const u16* g, u16* l) {
    __builtin_amdgcn_global_load_lds(
        (const __attribute__((address_space(1))) uint32_t*)g,
        (__attribute__((address_space(3))) uint32_t*)l,
        16, 0, 0);
}

// ---------------- GEMM core: C[M,N] = X[M,1024] @ W[1024,N] + bias ----------------
// WT = W^T bf16 [N][K]. 128x128 tile, BK=64, 2x2 wave quadrants, 4x4 16x16x32 frags.
// LDS tiles 128x64, unpadded, XOR-swizzled: physical 16B-block pb of row r holds
// logical block pb^(r&7) -> frag b128 reads are 2-way (free). B staged via async16
// (zero VGPRs); A staged via transient f32->bf16 VGPR pass when XF32 (qkv) or
// async16 when bf16 (oproj). No registers held across the compute phase (R5 spill fix).
// mode 0: bf16 scatter [B,H,S,D]; mode 1: f32 row-major; mode 2: bf16 V^T [BH,64,2048]
template<bool XF32>
__device__ __forceinline__ void gemm128(const void* __restrict__ Xv,
                                        const u16* __restrict__ WT,
                                        const float* __restrict__ bias,
                                        u16* __restrict__ dstb,
                                        float* __restrict__ dstf, int mode)
{
    __shared__ __align__(16) u16 As[128 * 64];
    __shared__ __align__(16) u16 Bs[128 * 64];
    const int t    = threadIdx.x;
    const int lane = t & 63;
    const int quad = lane >> 4;
    const int l15  = lane & 15;
    const int m0 = blockIdx.y * 128;
    const int n0 = blockIdx.x * 128;
    const int wave = t >> 6;
    const int wm = (wave >> 1) * 64;
    const int wn = (wave & 1) * 64;

    f32x4 acc[4][4];
#pragma unroll
    for (int i = 0; i < 4; i++)
#pragma unroll
        for (int j = 0; j < 4; j++)
#pragma unroll
            for (int r = 0; r < 4; r++) acc[i][j][r] = 0.0f;

    // staging chunk map: ci = c*256+t; row r=ci>>3, physical block pb=ci&7,
    // logical (global) block lb = pb ^ (r&7)
    int rr[4], lb[4];
#pragma unroll
    for (int c = 0; c < 4; c++) {
        const int ci = c * 256 + t;
        rr[c] = ci >> 3;
        lb[c] = (ci & 7) ^ (rr[c] & 7);
    }

    for (int kt = 0; kt < 1024; kt += 64) {
        __syncthreads();                    // (a) prior tile's frag reads complete
#pragma unroll
        for (int c = 0; c < 4; c++)         // B: async DMA, no VGPRs
            async16(WT + (n0 + rr[c]) * 1024 + kt + lb[c] * 8, &Bs[(c * 256 + t) * 8]);
        if (XF32) {                         // A: f32 load -> bf16 pack -> LDS
#pragma unroll
            for (int c = 0; c < 4; c++) {
                const float* g = (const float*)Xv + (m0 + rr[c]) * 1024 + kt + lb[c] * 8;
                const float4 lo = *(const float4*)g;
                const float4 hi = *(const float4*)(g + 4);
                *(uint4*)&As[(c * 256 + t) * 8] = pack8(lo, hi);
            }
        } else {
#pragma unroll
            for (int c = 0; c < 4; c++)
                async16((const u16*)Xv + (m0 + rr[c]) * 1024 + kt + lb[c] * 8,
                        &As[(c * 256 + t) * 8]);
        }
        __syncthreads();                    // (b) vmcnt drained + staging visible

#pragma unroll
        for (int kk = 0; kk < 64; kk += 32) {
            bf16x8 af[4], bfv[4];
#pragma unroll
            for (int i = 0; i < 4; i++) {
                const int ra = wm + i * 16 + l15;
                const int rb2 = wn + i * 16 + l15;
                af[i]  = *(const bf16x8*)&As[ra * 64 + (((kk >> 3) + quad) ^ (l15 & 7)) * 8];
                bfv[i] = *(const bf16x8*)&Bs[rb2 * 64 + (((kk >> 3) + quad) ^ (l15 & 7)) * 8];
            }
#pragma unroll
            for (int i = 0; i < 4; i++)
#pragma unroll
                for (int j = 0; j < 4; j++)
                    acc[i][j] = __builtin_amdgcn_mfma_f32_16x16x32_bf16(af[i], bfv[j], acc[i][j], 0, 0, 0);
        }
    }

    // epilogue: C row = quad*4 + r, col = lane&15 (HW-verified R4)
#pragma unroll
    for (int i = 0; i < 4; i++) {
        const int rb = m0 + wm + i * 16 + quad * 4;
#pragma unroll
        for (int j = 0; j < 4; j++) {
            const int col = n0 + wn + j * 16 + l15;
            const float bias_v = bias[col];
            if (mode == 2) {
                // V^T direct store: 4 consecutive s at fixed (h,d) -> packed b64
                const int b = rb >> 11, s = rb & 2047;
                const int h = col >> 6, d = col & 63;
                uint2 pk;
                pk.x = pk2(acc[i][j][0] + bias_v, acc[i][j][1] + bias_v);
                pk.y = pk2(acc[i][j][2] + bias_v, acc[i][j][3] + bias_v);
                *(uint2*)&dstb[((b * 16 + h) * 64 + d) * 2048 + s] = pk;
            } else {
#pragma unroll
                for (int r = 0; r < 4; r++) {
                    const float v = acc[i][j][r] + bias_v;
                    const int gm = rb + r;
                    if (mode == 0) {
                        const int b = gm >> 11, s = gm & 2047;
                        const int h = col >> 6, d = col & 63;
                        dstb[((b * 16 + h) * 2048 + s) * 64 + d] = f2b(v);
                    } else {
                        dstf[gm * 1024 + col] = v;
                    }
                }
            }
        }
    }
}

__global__ __launch_bounds__(256)
void qkv_kernel(const float* __restrict__ q_in, const float* __restrict__ k_in,
                const float* __restrict__ v_in, const u16* __restrict__ WT,
                const float* __restrict__ bq, const float* __restrict__ bk,
                const float* __restrict__ bv,
                u16* __restrict__ Qo, u16* __restrict__ Ko, u16* __restrict__ VTo)
{
    const int z = blockIdx.z;
    const float* X   = (z == 0) ? q_in : (z == 1) ? k_in : v_in;
    const u16* wt    = WT + ((z == 0) ? 2 : (z == 1) ? 1 : 0) * (1024 * 1024);
    const float* bias= (z == 0) ? bq : (z == 1) ? bk : bv;
    u16* dst         = (z == 0) ? Qo : (z == 1) ? Ko : VTo;
    gemm128<true>(X, wt, bias, dst, nullptr, (z == 2) ? 2 : 0);
}

__global__ __launch_bounds__(256)
void oproj_kernel(const u16* __restrict__ AO, const u16* __restrict__ WT,
                  const float* __restrict__ bo, float* __restrict__ out)
{
    gemm128<false>(AO, WT + 3 * 1024 * 1024, bo, nullptr, out, 1);
}

// ---------------- weight transpose+cvt: W[1024 k][1024 n] f32 -> WT[n][k] bf16 ----
__global__ void transpose_w(const float* __restrict__ Wv, const float* __restrict__ Wk,
                            const float* __restrict__ Wq, const float* __restrict__ Wo,
                            u16* __restrict__ WT)
{
    __shared__ u16 tile[64][65];
    const int z = blockIdx.z;
    const float* W = (z == 0) ? Wv : (z == 1) ? Wk : (z == 2) ? Wq : Wo;
    u16* dst = WT + z * 1024 * 1024;
    const int r0 = blockIdx.y * 64, c0 = blockIdx.x * 64;
    const int col = threadIdx.x & 63, rb = threadIdx.x >> 6;
#pragma unroll
    for (int r = rb; r < 64; r += 4) tile[r][col] = f2b(W[(r0 + r) * 1024 + c0 + col]);
    __syncthreads();
#pragma unroll
    for (int r = rb; r < 64; r += 4) dst[(c0 + r) * 1024 + r0 + col] = tile[col][r];
}

// ---------------- flash attention (transposed): Tq=64/block, Tk=128 KV tiles -------
// S^T = K·Q^T -> per-lane online softmax (lane owns one q-row, 2 shuffles).
// K/V staged via async16 into unpadded XOR-swizzled LDS (no prefetch regs -> no
// spill). P^T round-trips through swizzled stride-128 LDS, wave-private rows,
// fenced with lgkmcnt. O^T = V^T·P^T. 2 barriers/iter.
__global__ __launch_bounds__(256, 2)
void attn_kernel(const u16* __restrict__ Q, const u16* __restrict__ K,
                 const u16* __restrict__ VT, u16* __restrict__ AO)
{
    __shared__ __align__(16) u16 Qs[64 * 72];     // padded (VGPR-staged once)
    __shared__ __align__(16) u16 Ks[128 * 64];    // swizzle r&7
    __shared__ __align__(16) u16 Vts[64 * 128];   // swizzle r&15
    __shared__ __align__(16) u16 Ps[64 * 128];    // swizzle r&15

    const int t    = threadIdx.x;
    const int lane = t & 63;
    const int wave = t >> 6;
    const int quad = lane >> 4;
    const int l15  = lane & 15;
    const int bh = blockIdx.y;
    const int qt = blockIdx.x;

    const u16* Qg = Q + (bh * 2048 + qt * 64) * 64;
    const u16* Kg = K + bh * 2048 * 64;
    const u16* Vg = VT + bh * 64 * 2048;

    // stage Q once; fold 0.125*log2(e) so softmax runs in exp2 domain
#pragma unroll
    for (int c = 0; c < 2; c++) {
        const int chunk = t + c * 256;
        const int row = chunk >> 3;
        const int col = (chunk & 7) * 8;
        uint4 dv = *(const uint4*)&Qg[row * 64 + col];
        u16 tmp[8];
        *(uint4*)tmp = dv;
        float f[8];
#pragma unroll
        for (int i = 0; i < 8; i++) {
            union { float f; uint32_t u; } x; x.u = ((uint32_t)tmp[i]) << 16;
            f[i] = x.f * 0.18033688f;   // 0.125 * log2e
        }
        uint4 pk;
        pk.x = pk2(f[0], f[1]); pk.y = pk2(f[2], f[3]);
        pk.z = pk2(f[4], f[5]); pk.w = pk2(f[6], f[7]);
        *(uint4*)&Qs[row * 72 + col] = pk;
    }

    f32x4 o[4];
#pragma unroll
    for (int dj = 0; dj < 4; dj++)
#pragma unroll
        for (int r = 0; r < 4; r++) o[dj][r] = 0.0f;
    float m_st = -1.0e30f, l_st = 0.0f;

    // staging maps (linear LDS chunk ci = c*256+t)
    int krr[4], klb[4], vrr[4], vlb[4];
#pragma unroll
    for (int c = 0; c < 4; c++) {
        const int ci = c * 256 + t;
        krr[c] = ci >> 3;  klb[c] = (ci & 7)  ^ (krr[c] & 7);
        vrr[c] = ci >> 4;  vlb[c] = (ci & 15) ^ (vrr[c] & 15);
    }

    for (int kv = 0; kv < 16; kv++) {
        const int j0 = kv * 128;
        __syncthreads();   // (a) prev tile's LDS reads done
#pragma unroll
        for (int c = 0; c < 4; c++) {
            async16(Kg + (j0 + krr[c]) * 64 + klb[c] * 8, &Ks[(c * 256 + t) * 8]);
            async16(Vg + vrr[c] * 2048 + j0 + vlb[c] * 8, &Vts[(c * 256 + t) * 8]);
        }
        __syncthreads();   // (b) DMA drained (vmcnt 0 before barrier) + visible

        // S^T = K·Q^T : A-frags = K rows (kv), B-frag = this wave's q-rows
        f32x4 s[8];
#pragma unroll
        for (int n = 0; n < 8; n++)
#pragma unroll
            for (int r = 0; r < 4; r++) s[n][r] = 0.0f;
#pragma unroll
        for (int kk = 0; kk < 64; kk += 32) {
            const bf16x8 bq = *(const bf16x8*)&Qs[(wave * 16 + l15) * 72 + kk + quad * 8];
#pragma unroll
            for (int n = 0; n < 8; n++) {
                const bf16x8 ak = *(const bf16x8*)
                    &Ks[(n * 16 + l15) * 64 + (((kk >> 3) + quad) ^ (l15 & 7)) * 8];
                s[n] = __builtin_amdgcn_mfma_f32_16x16x32_bf16(ak, bq, s[n], 0, 0, 0);
            }
        }

        // per-lane online softmax (q-row = l15 of this wave's 16)
        float mx = s[0][0];
#pragma unroll
        for (int n = 0; n < 8; n++)
#pragma unroll
            for (int r = 0; r < 4; r++) mx = fmaxf(mx, s[n][r]);
        mx = fmaxf(mx, __shfl_xor(mx, 16));
        mx = fmaxf(mx, __shfl_xor(mx, 32));
        const float mnew = fmaxf(m_st, mx);
        const float alpha = exp2f(m_st - mnew);
        m_st = mnew;
        float sum = 0.0f;
#pragma unroll
        for (int n = 0; n < 8; n++)
#pragma unroll
            for (int r = 0; r < 4; r++) {
                const float p = exp2f(s[n][r] - m_st);
                s[n][r] = p;
                sum += p;
            }
        sum += __shfl_xor(sum, 16);
        sum += __shfl_xor(sum, 32);
        l_st = l_st * alpha + sum;
#pragma unroll
        for (int dj = 0; dj < 4; dj++)
#pragma unroll
            for (int r = 0; r < 4; r++) o[dj][r] *= alpha;

        // P^T[qrow][kv] -> swizzled LDS, packed b64 (4 consecutive kv cols)
#pragma unroll
        for (int n = 0; n < 8; n++) {
            const int pbw = ((2 * n + (quad >> 1)) ^ l15);
            uint2 pk;
            pk.x = pk2(s[n][0], s[n][1]);
            pk.y = pk2(s[n][2], s[n][3]);
            *(uint2*)&Ps[(wave * 16 + l15) * 128 + pbw * 8 + (quad & 1) * 4] = pk;
        }
        asm volatile("s_waitcnt lgkmcnt(0)" ::: "memory");  // wave-private RAW fence

        // O^T += V^T·P^T
#pragma unroll
        for (int ks = 0; ks < 4; ks++) {
#pragma unroll
            for (int dj = 0; dj < 4; dj++) {
                const bf16x8 av = *(const bf16x8*)
                    &Vts[(dj * 16 + l15) * 128 + ((ks * 4 + quad) ^ l15) * 8];
                const bf16x8 bp = *(const bf16x8*)
                    &Ps[(wave * 16 + l15) * 128 + ((ks * 4 + quad) ^ l15) * 8];
                o[dj] = __builtin_amdgcn_mfma_f32_16x16x32_bf16(av, bp, o[dj], 0, 0, 0);
            }
        }
    }

    // epilogue: O^T[d = dj*16+quad*4+r][qrow = l15]; write bf16 [B,S,E] packed b64
    const int b = bh >> 4, h = bh & 15;
    const int sq = qt * 64 + wave * 16 + l15;
    const float inv = 1.0f / l_st;
#pragma unroll
    for (int dj = 0; dj < 4; dj++) {
        uint2 pk;
        pk.x = pk2(o[dj][0] * inv, o[dj][1] * inv);
        pk.y = pk2(o[dj][2] * inv, o[dj][3] * inv);
        *(uint2*)&AO[(b * 2048 + sq) * 1024 + h * 64 + dj * 16 + quad * 4] = pk;
    }
}

extern "C" void kernel_launch(void* const* d_in, const int* in_sizes, int n_in,
                              void* d_out, int out_size, void* d_ws, size_t ws_size,
                              hipStream_t stream)
{
    (void)in_sizes; (void)n_in; (void)out_size; (void)ws_size;
    const float* value = (const float*)d_in[0];
    const float* key_  = (const float*)d_in[1];
    const float* query = (const float*)d_in[2];
    const float* Wv = (const float*)d_in[3];
    const float* bv = (const float*)d_in[4];
    const float* Wk = (const float*)d_in[5];
    const float* bk = (const float*)d_in[6];
    const float* Wq = (const float*)d_in[7];
    const float* bq = (const float*)d_in[8];
    const float* Wo = (const float*)d_in[9];
    const float* bo = (const float*)d_in[10];

    u16* ws = (u16*)d_ws;
    u16* WT = ws;                          // 4 x 1M bf16 (order: v,k,q,o)
    u16* Q  = ws + 4 * 1024 * 1024;        // 8M bf16 [B,H,S,D]
    u16* K  = Q + 8 * 1024 * 1024;         // 8M [B,H,S,D]
    u16* VT = K + 8 * 1024 * 1024;         // 8M [B,H,D,S] (written directly by qkv)
    u16* AO = VT + 8 * 1024 * 1024;        // 8M [B*S, E]   (total 72 MB, proven)

    transpose_w<<<dim3(16, 16, 4), dim3(256), 0, stream>>>(Wv, Wk, Wq, Wo, WT);
    qkv_kernel<<<dim3(8, 64, 3), dim3(256), 0, stream>>>(query, key_, value, WT,
                                                         bq, bk, bv, Q, K, VT);
    attn_kernel<<<dim3(32, 64), dim3(256), 0, stream>>>(Q, K, VT, AO);
    oproj_kernel<<<dim3(8, 64, 1), dim3(256), 0, stream>>>(AO, WT, bo, (float*)d_out);
}